// Round 1
// baseline (39.885 us; speedup 1.0000x reference)
//
#include <hip/hip_runtime.h>

// Problem constants (from setup_inputs): B=32, A=5, H=W=52, T=50
#define BB 32
#define AA 5
#define HH 52
#define WW 52
#define TT 50

#define HW (HH * WW)          // 2704
#define AHW (AA * HW)         // 13520
#define N1 (BB * AA * HW)     // 432640  (obj-shaped planes)
#define N2 (BB * 2 * AA * HW) // 865280  (xy-shaped planes)

// ---------------------------------------------------------------------------
// Phase 1: per-truth anchor argmax + winner assignment via atomicMax.
// Reproduces: n = argmax_a iou2; cell = ((b*A+n)*H+tj)*W+ti;
//             winner = full(-1).at[cell].max(t, mode='drop')
// ---------------------------------------------------------------------------
__global__ void assign_kernel(const float* __restrict__ truth,
                              const float* __restrict__ biases,
                              int* __restrict__ winner) {
    int idx = blockIdx.x * blockDim.x + threadIdx.x;
    if (idx >= BB * TT) return;
    int b = idx / TT;
    int t = idx - b * TT;
    const float* tr = truth + (b * TT + t) * 5;
    float tx = tr[0], ty = tr[1], tw = tr[2], th = tr[3];

    // argmax over anchors of centered-box IoU (first max wins, like jnp.argmax)
    float best = -1.0f;
    int n = 0;
#pragma unroll
    for (int a = 0; a < AA; ++a) {
        float bw0 = biases[2 * a] / (float)WW;
        float bh0 = biases[2 * a + 1] / (float)HH;
        float il2 = fmaxf(-bw0 * 0.5f, -tw * 0.5f);
        float ir2 = fminf(bw0 * 0.5f, tw * 0.5f);
        float it2 = fmaxf(-bh0 * 0.5f, -th * 0.5f);
        float ib2 = fminf(bh0 * 0.5f, th * 0.5f);
        float ov2 = fmaxf(ir2 - il2, 0.0f) * fmaxf(ib2 - it2, 0.0f);
        float iou2 = ov2 / (bw0 * bh0 + tw * th - ov2);
        if (iou2 > best) { best = iou2; n = a; }
    }

    int ti = (int)(tx * (float)WW);   // truncation toward zero, matches astype(int32)
    int tj = (int)(ty * (float)HH);
    bool invalid_pos = (tx <= 0.0f) || (tx >= 1.0f) || (ty <= 0.0f) || (ty >= 1.0f);
    bool valid = !invalid_pos && ti >= 0 && tj >= 0 && ti < WW && tj < HH &&
                 (tw > 0.0f) && (th > 0.0f);
    if (valid) {
        int cell = ((b * AA + n) * HH + tj) * WW + ti;
        atomicMax(&winner[cell], t);
    }
}

// ---------------------------------------------------------------------------
// Phase 2: per-cell targets. grid = (ceil(AHW/256), B); block owns one image b
// so truth[b] (250 floats) is staged in LDS once per block.
// ---------------------------------------------------------------------------
__global__ __launch_bounds__(256) void region_target_kernel(
    const float* __restrict__ xy, const float* __restrict__ wh,
    const float* __restrict__ obj, const float* __restrict__ truth,
    const float* __restrict__ biases, const int* __restrict__ winner,
    float* __restrict__ out) {
    __shared__ float s_truth[TT * 5];
    __shared__ float s_bias[2 * AA];

    int b = blockIdx.y;
    int tid = threadIdx.x;
    for (int k = tid; k < TT * 5; k += 256) s_truth[k] = truth[b * TT * 5 + k];
    if (tid < 2 * AA) s_bias[tid] = biases[tid];
    __syncthreads();

    int cell = blockIdx.x * 256 + tid;
    if (cell >= AHW) return;
    int a = cell / HW;
    int rem = cell - a * HW;
    int j = rem / WW;
    int i = rem - j * WW;

    // flat indices
    int base2  = ((b * 2 * AA + a) * HH + j) * WW + i;        // x-half channel a
    int base2h = ((b * 2 * AA + AA + a) * HH + j) * WW + i;   // y-half channel A+a
    int base1  = ((b * AA + a) * HH + j) * WW + i;

    float x  = xy[base2];
    float y  = xy[base2h];
    float w_ = wh[base2];
    float h_ = wh[base2h];
    float o  = obj[base1];

    float ba0 = s_bias[2 * a], ba1 = s_bias[2 * a + 1];

    // predicted box (mirror reference op order exactly)
    float bx = (x + (float)i) / (float)WW;
    float by = (y + (float)j) / (float)HH;
    float bw = expf(w_) * ba0 / (float)WW;
    float bh = expf(h_) * ba1 / (float)HH;

    float bxl = bx - bw * 0.5f, bxr = bx + bw * 0.5f;
    float byt = by - bh * 0.5f, byb = by + bh * 0.5f;
    float areap = bw * bh;

    // max IoU over all truths -> ignorable
    float maxiou = -INFINITY;
    for (int t = 0; t < TT; ++t) {
        float tx = s_truth[t * 5 + 0];
        float ty = s_truth[t * 5 + 1];
        float tw = s_truth[t * 5 + 2];
        float th = s_truth[t * 5 + 3];
        float il = fmaxf(bxl, tx - tw * 0.5f);
        float ir = fminf(bxr, tx + tw * 0.5f);
        float it = fmaxf(byt, ty - th * 0.5f);
        float ib = fminf(byb, ty + th * 0.5f);
        float ov = fmaxf(ir - il, 0.0f) * fmaxf(ib - it, 0.0f);
        float iou = ov / (areap + tw * th - ov);
        maxiou = fmaxf(maxiou, iou);
    }
    bool ignorable = maxiou > 0.6f;

    int wsel = winner[base1];
    bool has = wsel >= 0;
    int wi = has ? wsel : 0;
    float stx  = s_truth[wi * 5 + 0];
    float sty  = s_truth[wi * 5 + 1];
    float stw  = s_truth[wi * 5 + 2];
    float sth  = s_truth[wi * 5 + 3];
    float scls = s_truth[wi * 5 + 4];

    float t_xy0, t_xy1, t_wh0, t_wh1, wgt, t_obj, t_label;
    if (has) {
        t_xy0 = stx * (float)WW - (float)i;
        t_xy1 = sty * (float)HH - (float)j;
        t_wh0 = logf(stw * (float)WW / ba0);
        t_wh1 = logf(sth * (float)HH / ba1);
        wgt   = 2.0f - stw * sth;          // COORD_SCALE = 1.0
        // IoU with the selected truth (rescore)
        float il = fmaxf(bxl, stx - stw * 0.5f);
        float ir = fminf(bxr, stx + stw * 0.5f);
        float it = fmaxf(byt, sty - sth * 0.5f);
        float ib = fminf(byb, sty + sth * 0.5f);
        float ov = fmaxf(ir - il, 0.0f) * fmaxf(ib - it, 0.0f);
        t_obj   = ov / (areap + stw * sth - ov);
        t_label = scls;
    } else {
        t_xy0 = x;  t_xy1 = y;
        t_wh0 = w_; t_wh1 = h_;
        wgt   = 0.0f;
        t_obj = o;
        t_label = -1.0f;
    }
    float t_noobj = (has || ignorable) ? o : 0.0f;

    // outputs, concatenated flat in return order
    out[base2]               = t_xy0;   // t_xy (x half)
    out[base2h]              = t_xy1;   // t_xy (y half)
    out[N2 + base2]          = t_wh0;   // t_wh
    out[N2 + base2h]         = t_wh1;
    out[2 * N2 + base2]      = wgt;     // t_xywh_weight (both halves)
    out[2 * N2 + base2h]     = wgt;
    out[3 * N2 + base1]      = t_obj;   // t_o_obj
    out[3 * N2 + N1 + base1] = t_noobj; // t_o_noobj
    out[3 * N2 + 2 * N1 + base1] = t_label; // t_label
}

extern "C" void kernel_launch(void* const* d_in, const int* in_sizes, int n_in,
                              void* d_out, int out_size, void* d_ws, size_t ws_size,
                              hipStream_t stream) {
    const float* xy     = (const float*)d_in[0];
    const float* wh     = (const float*)d_in[1];
    const float* obj    = (const float*)d_in[2];
    const float* truth  = (const float*)d_in[3];
    const float* biases = (const float*)d_in[4];
    float* out = (float*)d_out;
    int* winner = (int*)d_ws;

    // winner = -1 everywhere (0xFF bytes == -1 as int32); graph-capture legal
    hipMemsetAsync(winner, 0xFF, (size_t)N1 * sizeof(int), stream);

    // Phase 1: 1600 truths
    assign_kernel<<<(BB * TT + 255) / 256, 256, 0, stream>>>(truth, biases, winner);

    // Phase 2: one thread per (a,j,i) cell, one image per block row
    dim3 grid((AHW + 255) / 256, BB);
    region_target_kernel<<<grid, 256, 0, stream>>>(xy, wh, obj, truth, biases,
                                                   winner, out);
}

// Round 2
// 27.642 us; speedup vs baseline: 1.4429x; 1.4429x over previous
//
#include <hip/hip_runtime.h>

// Problem constants (from setup_inputs): B=32, A=5, H=W=52, T=50
#define BB 32
#define AA 5
#define HH 52
#define WW 52
#define TT 50

#define HW (HH * WW)          // 2704
#define AHW (AA * HW)         // 13520
#define N1 (BB * AA * HW)     // 432640  (obj-shaped planes)
#define N2 (BB * 2 * AA * HW) // 865280  (xy-shaped planes)

// ---------------------------------------------------------------------------
// Single fused kernel. grid = (ceil(AHW/256), B); each block serves one image.
// Block prologue (LDS):
//   - stage truth[b] (250 floats)
//   - threads 0..49: per-truth anchor argmax -> packed local cell id (or -1)
// Per cell: one 50-iter loop computes BOTH max-IoU (ignorable) and the
// winner (max t whose packed cell == this cell; ascending loop, last match).
// This removes the dense winner buffer, its 40us memset, and a kernel launch.
// ---------------------------------------------------------------------------
__global__ __launch_bounds__(256) void region_target_fused(
    const float* __restrict__ xy, const float* __restrict__ wh,
    const float* __restrict__ obj, const float* __restrict__ truth,
    const float* __restrict__ biases, float* __restrict__ out) {
    __shared__ float s_truth[TT * 5];
    __shared__ int   s_cell[TT];
    __shared__ float s_bias[2 * AA];

    int b = blockIdx.y;
    int tid = threadIdx.x;

    if (tid < TT * 5) s_truth[tid] = truth[b * TT * 5 + tid];
    if (tid < 2 * AA) s_bias[tid] = biases[tid];
    __syncthreads();   // s_truth/s_bias ready for the assign step below

    if (tid < TT) {
        float tx = s_truth[tid * 5 + 0];
        float ty = s_truth[tid * 5 + 1];
        float tw = s_truth[tid * 5 + 2];
        float th = s_truth[tid * 5 + 3];
        // argmax over anchors of centered-box IoU (first max wins, like jnp.argmax)
        float best = -1.0f;
        int n = 0;
#pragma unroll
        for (int a = 0; a < AA; ++a) {
            float bw0 = s_bias[2 * a] / (float)WW;
            float bh0 = s_bias[2 * a + 1] / (float)HH;
            float il2 = fmaxf(-bw0 * 0.5f, -tw * 0.5f);
            float ir2 = fminf(bw0 * 0.5f, tw * 0.5f);
            float it2 = fmaxf(-bh0 * 0.5f, -th * 0.5f);
            float ib2 = fminf(bh0 * 0.5f, th * 0.5f);
            float ov2 = fmaxf(ir2 - il2, 0.0f) * fmaxf(ib2 - it2, 0.0f);
            float iou2 = ov2 / (bw0 * bh0 + tw * th - ov2);
            if (iou2 > best) { best = iou2; n = a; }
        }
        int ti = (int)(tx * (float)WW);   // trunc toward zero == astype(int32) for tx>0
        int tj = (int)(ty * (float)HH);
        bool invalid_pos = (tx <= 0.0f) || (tx >= 1.0f) || (ty <= 0.0f) || (ty >= 1.0f);
        bool valid = !invalid_pos && ti >= 0 && tj >= 0 && ti < WW && tj < HH &&
                     (tw > 0.0f) && (th > 0.0f);
        s_cell[tid] = valid ? ((n * HH + tj) * WW + ti) : -1;
    }
    __syncthreads();

    int cell = blockIdx.x * 256 + tid;
    if (cell >= AHW) return;
    int a = cell / HW;
    int rem = cell - a * HW;
    int j = rem / WW;
    int i = rem - j * WW;

    // flat indices
    int base2  = ((b * 2 * AA + a) * HH + j) * WW + i;        // x-half channel a
    int base2h = ((b * 2 * AA + AA + a) * HH + j) * WW + i;   // y-half channel A+a
    int base1  = ((b * AA + a) * HH + j) * WW + i;

    float x  = xy[base2];
    float y  = xy[base2h];
    float w_ = wh[base2];
    float h_ = wh[base2h];
    float o  = obj[base1];

    float ba0 = s_bias[2 * a], ba1 = s_bias[2 * a + 1];

    // predicted box (mirror reference op order exactly)
    float bx = (x + (float)i) / (float)WW;
    float by = (y + (float)j) / (float)HH;
    float bw = expf(w_) * ba0 / (float)WW;
    float bh = expf(h_) * ba1 / (float)HH;

    float bxl = bx - bw * 0.5f, bxr = bx + bw * 0.5f;
    float byt = by - bh * 0.5f, byb = by + bh * 0.5f;
    float areap = bw * bh;

    int mycell = rem + a * 0;                 // local (a,j,i) packed id
    mycell = (a * HH + j) * WW + i;

    // One pass over truths: max IoU (ignorable) + winner (last/maximal t match)
    float maxiou = -INFINITY;
    int wsel = -1;
    for (int t = 0; t < TT; ++t) {
        float tx = s_truth[t * 5 + 0];
        float ty = s_truth[t * 5 + 1];
        float tw = s_truth[t * 5 + 2];
        float th = s_truth[t * 5 + 3];
        float il = fmaxf(bxl, tx - tw * 0.5f);
        float ir = fminf(bxr, tx + tw * 0.5f);
        float it = fmaxf(byt, ty - th * 0.5f);
        float ib = fminf(byb, ty + th * 0.5f);
        float ov = fmaxf(ir - il, 0.0f) * fmaxf(ib - it, 0.0f);
        float iou = ov / (areap + tw * th - ov);
        maxiou = fmaxf(maxiou, iou);
        if (s_cell[t] == mycell) wsel = t;    // ascending t: last match == max t
    }
    bool ignorable = maxiou > 0.6f;

    bool has = wsel >= 0;
    int wi = has ? wsel : 0;
    float stx  = s_truth[wi * 5 + 0];
    float sty  = s_truth[wi * 5 + 1];
    float stw  = s_truth[wi * 5 + 2];
    float sth  = s_truth[wi * 5 + 3];
    float scls = s_truth[wi * 5 + 4];

    float t_xy0, t_xy1, t_wh0, t_wh1, wgt, t_obj, t_label;
    if (has) {
        t_xy0 = stx * (float)WW - (float)i;
        t_xy1 = sty * (float)HH - (float)j;
        t_wh0 = logf(stw * (float)WW / ba0);
        t_wh1 = logf(sth * (float)HH / ba1);
        wgt   = 2.0f - stw * sth;          // COORD_SCALE = 1.0
        // IoU with the selected truth (rescore)
        float il = fmaxf(bxl, stx - stw * 0.5f);
        float ir = fminf(bxr, stx + stw * 0.5f);
        float it = fmaxf(byt, sty - sth * 0.5f);
        float ib = fminf(byb, sty + sth * 0.5f);
        float ov = fmaxf(ir - il, 0.0f) * fmaxf(ib - it, 0.0f);
        t_obj   = ov / (areap + stw * sth - ov);
        t_label = scls;
    } else {
        t_xy0 = x;  t_xy1 = y;
        t_wh0 = w_; t_wh1 = h_;
        wgt   = 0.0f;
        t_obj = o;
        t_label = -1.0f;
    }
    float t_noobj = (has || ignorable) ? o : 0.0f;

    // outputs, concatenated flat in return order
    out[base2]               = t_xy0;   // t_xy (x half)
    out[base2h]              = t_xy1;   // t_xy (y half)
    out[N2 + base2]          = t_wh0;   // t_wh
    out[N2 + base2h]         = t_wh1;
    out[2 * N2 + base2]      = wgt;     // t_xywh_weight (both halves)
    out[2 * N2 + base2h]     = wgt;
    out[3 * N2 + base1]      = t_obj;   // t_o_obj
    out[3 * N2 + N1 + base1] = t_noobj; // t_o_noobj
    out[3 * N2 + 2 * N1 + base1] = t_label; // t_label
}

extern "C" void kernel_launch(void* const* d_in, const int* in_sizes, int n_in,
                              void* d_out, int out_size, void* d_ws, size_t ws_size,
                              hipStream_t stream) {
    const float* xy     = (const float*)d_in[0];
    const float* wh     = (const float*)d_in[1];
    const float* obj    = (const float*)d_in[2];
    const float* truth  = (const float*)d_in[3];
    const float* biases = (const float*)d_in[4];
    float* out = (float*)d_out;

    dim3 grid((AHW + 255) / 256, BB);
    region_target_fused<<<grid, 256, 0, stream>>>(xy, wh, obj, truth, biases, out);
}

// Round 3
// 26.202 us; speedup vs baseline: 1.5222x; 1.0550x over previous
//
#include <hip/hip_runtime.h>

// Problem constants (from setup_inputs): B=32, A=5, H=W=52, T=50
#define BB 32
#define AA 5
#define HH 52
#define WW 52
#define TT 50

#define HW (HH * WW)          // 2704
#define AHW (AA * HW)         // 13520
#define N1 (BB * AA * HW)     // 432640  (obj-shaped planes)
#define N2 (BB * 2 * AA * HW) // 865280  (xy-shaped planes)

// ---------------------------------------------------------------------------
// Single fused kernel. grid = (ceil(AHW/256), B); each block serves one image.
// Prologue (LDS):
//   - stage truth[b] (250 floats) + biases
//   - threads 0..49: per-truth precompute: box edges as float4 (one
//     ds_read_b128/iter, wave-uniform broadcast), 0.6*area as float,
//     and anchor-argmax cell -> LDS winner map s_win[256] via shared atomicMax
//     (cell == cellbase + tid, so the main pass reads s_win[tid] directly).
// Main loop per cell: 50 iters, NO division:
//   iou > 0.6  <=>  1.6*ov - 0.6*tarea > 0.6*areap   (union > 0 always)
// Only the winner's rescore IoU (<=1 per thread) uses a real divide.
// ---------------------------------------------------------------------------
__global__ __launch_bounds__(256) void region_target_fused(
    const float* __restrict__ xy, const float* __restrict__ wh,
    const float* __restrict__ obj, const float* __restrict__ truth,
    const float* __restrict__ biases, float* __restrict__ out) {
    __shared__ float  s_truth[TT * 5];
    __shared__ float4 s_tbox[TT];     // (txl, txr, tyt, tyb)
    __shared__ float  s_t06[TT];      // 0.6 * tw * th
    __shared__ float  s_bias[2 * AA];
    __shared__ int    s_win[256];     // winner t per local cell, -1 = none

    int b = blockIdx.y;
    int tid = threadIdx.x;
    int cellbase = blockIdx.x * 256;

    if (tid < TT * 5) s_truth[tid] = truth[b * TT * 5 + tid];
    if (tid < 2 * AA) s_bias[tid] = biases[tid];
    s_win[tid] = -1;
    __syncthreads();

    if (tid < TT) {
        float tx = s_truth[tid * 5 + 0];
        float ty = s_truth[tid * 5 + 1];
        float tw = s_truth[tid * 5 + 2];
        float th = s_truth[tid * 5 + 3];
        s_tbox[tid] = make_float4(tx - tw * 0.5f, tx + tw * 0.5f,
                                  ty - th * 0.5f, ty + th * 0.5f);
        s_t06[tid] = 0.6f * (tw * th);

        // argmax over anchors of centered-box IoU (first max wins, like jnp.argmax)
        float best = -1.0f;
        int n = 0;
#pragma unroll
        for (int a = 0; a < AA; ++a) {
            float bw0 = s_bias[2 * a] / (float)WW;
            float bh0 = s_bias[2 * a + 1] / (float)HH;
            float il2 = fmaxf(-bw0 * 0.5f, -tw * 0.5f);
            float ir2 = fminf(bw0 * 0.5f, tw * 0.5f);
            float it2 = fmaxf(-bh0 * 0.5f, -th * 0.5f);
            float ib2 = fminf(bh0 * 0.5f, th * 0.5f);
            float ov2 = fmaxf(ir2 - il2, 0.0f) * fmaxf(ib2 - it2, 0.0f);
            float iou2 = ov2 / (bw0 * bh0 + tw * th - ov2);
            if (iou2 > best) { best = iou2; n = a; }
        }
        int ti = (int)(tx * (float)WW);   // trunc toward zero == astype(int32) for tx>0
        int tj = (int)(ty * (float)HH);
        bool invalid_pos = (tx <= 0.0f) || (tx >= 1.0f) || (ty <= 0.0f) || (ty >= 1.0f);
        bool valid = !invalid_pos && ti >= 0 && tj >= 0 && ti < WW && tj < HH &&
                     (tw > 0.0f) && (th > 0.0f);
        if (valid) {
            int local = (n * HH + tj) * WW + ti - cellbase;
            if (local >= 0 && local < 256) atomicMax(&s_win[local], tid);
        }
    }
    __syncthreads();

    int cell = cellbase + tid;
    if (cell >= AHW) return;
    int a = cell / HW;
    int rem = cell - a * HW;
    int j = rem / WW;
    int i = rem - j * WW;

    // flat indices
    int base2  = ((b * 2 * AA + a) * HH + j) * WW + i;        // x-half channel a
    int base2h = ((b * 2 * AA + AA + a) * HH + j) * WW + i;   // y-half channel A+a
    int base1  = ((b * AA + a) * HH + j) * WW + i;

    float x  = xy[base2];
    float y  = xy[base2h];
    float w_ = wh[base2];
    float h_ = wh[base2h];
    float o  = obj[base1];

    float ba0 = s_bias[2 * a], ba1 = s_bias[2 * a + 1];

    // predicted box (mirror reference op order exactly)
    float bx = (x + (float)i) / (float)WW;
    float by = (y + (float)j) / (float)HH;
    float bw = expf(w_) * ba0 / (float)WW;
    float bh = expf(h_) * ba1 / (float)HH;

    float bxl = bx - bw * 0.5f, bxr = bx + bw * 0.5f;
    float byt = by - bh * 0.5f, byb = by + bh * 0.5f;
    float areap = bw * bh;
    float thresh = 0.6f * areap;

    // division-free max over truths of (1.6*ov - 0.6*tarea)
    float m = -1e30f;
#pragma unroll 10
    for (int t = 0; t < TT; ++t) {
        float4 tb = s_tbox[t];
        float il = fmaxf(bxl, tb.x);
        float ir = fminf(bxr, tb.y);
        float it = fmaxf(byt, tb.z);
        float ib = fminf(byb, tb.w);
        float ov = fmaxf(ir - il, 0.0f) * fmaxf(ib - it, 0.0f);
        m = fmaxf(m, fmaf(1.6f, ov, -s_t06[t]));
    }
    bool ignorable = m > thresh;

    int wsel = s_win[tid];
    bool has = wsel >= 0;
    int wi = has ? wsel : 0;
    float stx  = s_truth[wi * 5 + 0];
    float sty  = s_truth[wi * 5 + 1];
    float stw  = s_truth[wi * 5 + 2];
    float sth  = s_truth[wi * 5 + 3];
    float scls = s_truth[wi * 5 + 4];

    float t_xy0, t_xy1, t_wh0, t_wh1, wgt, t_obj, t_label;
    if (has) {
        t_xy0 = stx * (float)WW - (float)i;
        t_xy1 = sty * (float)HH - (float)j;
        t_wh0 = logf(stw * (float)WW / ba0);
        t_wh1 = logf(sth * (float)HH / ba1);
        wgt   = 2.0f - stw * sth;          // COORD_SCALE = 1.0
        // IoU with the selected truth (rescore) — exact formula incl. divide
        float il = fmaxf(bxl, stx - stw * 0.5f);
        float ir = fminf(bxr, stx + stw * 0.5f);
        float it = fmaxf(byt, sty - sth * 0.5f);
        float ib = fminf(byb, sty + sth * 0.5f);
        float ov = fmaxf(ir - il, 0.0f) * fmaxf(ib - it, 0.0f);
        t_obj   = ov / (areap + stw * sth - ov);
        t_label = scls;
    } else {
        t_xy0 = x;  t_xy1 = y;
        t_wh0 = w_; t_wh1 = h_;
        wgt   = 0.0f;
        t_obj = o;
        t_label = -1.0f;
    }
    float t_noobj = (has || ignorable) ? o : 0.0f;

    // outputs, concatenated flat in return order
    out[base2]               = t_xy0;   // t_xy (x half)
    out[base2h]              = t_xy1;   // t_xy (y half)
    out[N2 + base2]          = t_wh0;   // t_wh
    out[N2 + base2h]         = t_wh1;
    out[2 * N2 + base2]      = wgt;     // t_xywh_weight (both halves)
    out[2 * N2 + base2h]     = wgt;
    out[3 * N2 + base1]      = t_obj;   // t_o_obj
    out[3 * N2 + N1 + base1] = t_noobj; // t_o_noobj
    out[3 * N2 + 2 * N1 + base1] = t_label; // t_label
}

extern "C" void kernel_launch(void* const* d_in, const int* in_sizes, int n_in,
                              void* d_out, int out_size, void* d_ws, size_t ws_size,
                              hipStream_t stream) {
    const float* xy     = (const float*)d_in[0];
    const float* wh     = (const float*)d_in[1];
    const float* obj    = (const float*)d_in[2];
    const float* truth  = (const float*)d_in[3];
    const float* biases = (const float*)d_in[4];
    float* out = (float*)d_out;

    dim3 grid((AHW + 255) / 256, BB);
    region_target_fused<<<grid, 256, 0, stream>>>(xy, wh, obj, truth, biases, out);
}

// Round 4
// 23.362 us; speedup vs baseline: 1.7073x; 1.1216x over previous
//
#include <hip/hip_runtime.h>

// Problem constants (from setup_inputs): B=32, A=5, H=W=52, T=50
#define BB 32
#define AA 5
#define HH 52
#define WW 52
#define TT 50

#define HW (HH * WW)          // 2704  (divisible by 4)
#define AHW (AA * HW)         // 13520 (divisible by 4)
#define N1 (BB * AA * HW)     // 432640
#define N2 (BB * 2 * AA * HW) // 865280

#define CPT 4                  // cells per thread (share a,j; i%4==0 -> float4)
#define BLK 256
#define CPB (BLK * CPT)        // 1024 cells per block

// ---------------------------------------------------------------------------
// Fused, vectorized. grid = (ceil(AHW/1024), B). Each thread owns 4
// consecutive cells; since HW%4==0 and W%4==0 the 4 cells share (a,j) and
// i0%4==0, so every global access is an aligned float4 (1KB/wave).
// Prologue unchanged: truth staged to LDS; threads 0..49 do the per-truth
// anchor argmax (exact divide semantics preserved -> same winner as JAX) and
// scatter into the block-local winner map via LDS atomicMax.
// Inner 50-iter loop: division-free ignorable test, 2 LDS broadcasts/iter
// amortized over 4 cells, 4-way ILP.
// ---------------------------------------------------------------------------
__global__ __launch_bounds__(BLK) void region_target_fused(
    const float* __restrict__ xy, const float* __restrict__ wh,
    const float* __restrict__ obj, const float* __restrict__ truth,
    const float* __restrict__ biases, float* __restrict__ out) {
    __shared__ float  s_truth[TT * 5];
    __shared__ float4 s_tbox[TT];     // (txl, txr, tyt, tyb)
    __shared__ float  s_t06[TT];      // 0.6 * tw * th
    __shared__ float  s_bias[2 * AA];
    __shared__ int    s_win[CPB];     // winner t per local cell, -1 = none

    int b = blockIdx.y;
    int tid = threadIdx.x;
    int cellbase = blockIdx.x * CPB;

    if (tid < TT * 5) s_truth[tid] = truth[b * TT * 5 + tid];
    if (tid < 2 * AA) s_bias[tid] = biases[tid];
#pragma unroll
    for (int k = 0; k < CPT; ++k) s_win[tid + k * BLK] = -1;
    __syncthreads();

    if (tid < TT) {
        float tx = s_truth[tid * 5 + 0];
        float ty = s_truth[tid * 5 + 1];
        float tw = s_truth[tid * 5 + 2];
        float th = s_truth[tid * 5 + 3];
        s_tbox[tid] = make_float4(tx - tw * 0.5f, tx + tw * 0.5f,
                                  ty - th * 0.5f, ty + th * 0.5f);
        s_t06[tid] = 0.6f * (tw * th);

        // argmax over anchors (exact divide, first max wins == jnp.argmax)
        float best = -1.0f;
        int n = 0;
#pragma unroll
        for (int a = 0; a < AA; ++a) {
            float bw0 = s_bias[2 * a] / (float)WW;
            float bh0 = s_bias[2 * a + 1] / (float)HH;
            float il2 = fmaxf(-bw0 * 0.5f, -tw * 0.5f);
            float ir2 = fminf(bw0 * 0.5f, tw * 0.5f);
            float it2 = fmaxf(-bh0 * 0.5f, -th * 0.5f);
            float ib2 = fminf(bh0 * 0.5f, th * 0.5f);
            float ov2 = fmaxf(ir2 - il2, 0.0f) * fmaxf(ib2 - it2, 0.0f);
            float iou2 = ov2 / (bw0 * bh0 + tw * th - ov2);
            if (iou2 > best) { best = iou2; n = a; }
        }
        int ti = (int)(tx * (float)WW);
        int tj = (int)(ty * (float)HH);
        bool invalid_pos = (tx <= 0.0f) || (tx >= 1.0f) || (ty <= 0.0f) || (ty >= 1.0f);
        bool valid = !invalid_pos && ti >= 0 && tj >= 0 && ti < WW && tj < HH &&
                     (tw > 0.0f) && (th > 0.0f);
        if (valid) {
            int local = (n * HH + tj) * WW + ti - cellbase;
            if (local >= 0 && local < CPB) atomicMax(&s_win[local], tid);
        }
    }
    __syncthreads();

    int c0 = cellbase + tid * CPT;          // 4 cells c0..c0+3, c0%4==0
    if (c0 >= AHW) return;                  // AHW%4==0: no partial threads
    int a = c0 / HW;
    int rem = c0 - a * HW;
    int j = rem / WW;
    int i0 = rem - j * WW;                  // i0%4==0

    int base2  = ((b * 2 * AA + a) * HH + j) * WW + i0;   // x-half
    int base2h = base2 + AA * HW;                          // y-half (channel +A)
    int base1  = ((b * AA + a) * HH + j) * WW + i0;

    float4 x4 = *(const float4*)(xy + base2);
    float4 y4 = *(const float4*)(xy + base2h);
    float4 w4 = *(const float4*)(wh + base2);
    float4 h4 = *(const float4*)(wh + base2h);
    float4 o4 = *(const float4*)(obj + base1);

    float ba0 = s_bias[2 * a], ba1 = s_bias[2 * a + 1];

    float xs[CPT] = {x4.x, x4.y, x4.z, x4.w};
    float ys[CPT] = {y4.x, y4.y, y4.z, y4.w};
    float ws[CPT] = {w4.x, w4.y, w4.z, w4.w};
    float hs[CPT] = {h4.x, h4.y, h4.z, h4.w};
    float os[CPT] = {o4.x, o4.y, o4.z, o4.w};

    float bxl[CPT], bxr[CPT], byt[CPT], byb[CPT], areap[CPT], m[CPT];
#pragma unroll
    for (int k = 0; k < CPT; ++k) {
        float bx = (xs[k] + (float)(i0 + k)) / (float)WW;   // exact ref order
        float by = (ys[k] + (float)j) / (float)HH;
        float bw = expf(ws[k]) * ba0 / (float)WW;
        float bh = expf(hs[k]) * ba1 / (float)HH;
        bxl[k] = bx - bw * 0.5f; bxr[k] = bx + bw * 0.5f;
        byt[k] = by - bh * 0.5f; byb[k] = by + bh * 0.5f;
        areap[k] = bw * bh;
        m[k] = -1e30f;
    }

    // division-free: iou>0.6 <=> 1.6*ov - 0.6*tarea > 0.6*areap (union>0)
    for (int t = 0; t < TT; ++t) {
        float4 tb = s_tbox[t];
        float t06 = s_t06[t];
#pragma unroll
        for (int k = 0; k < CPT; ++k) {
            float il = fmaxf(bxl[k], tb.x);
            float ir = fminf(bxr[k], tb.y);
            float it = fmaxf(byt[k], tb.z);
            float ib = fminf(byb[k], tb.w);
            float ov = fmaxf(ir - il, 0.0f) * fmaxf(ib - it, 0.0f);
            m[k] = fmaxf(m[k], fmaf(1.6f, ov, -t06));
        }
    }

    float vxy0[CPT], vxy1[CPT], vwh0[CPT], vwh1[CPT], vwgt[CPT];
    float vobj[CPT], vnoobj[CPT], vlab[CPT];
#pragma unroll
    for (int k = 0; k < CPT; ++k) {
        bool ignorable = m[k] > 0.6f * areap[k];
        int wsel = s_win[tid * CPT + k];
        bool has = wsel >= 0;
        if (has) {
            int wi = wsel;
            float stx  = s_truth[wi * 5 + 0];
            float sty  = s_truth[wi * 5 + 1];
            float stw  = s_truth[wi * 5 + 2];
            float sth  = s_truth[wi * 5 + 3];
            vxy0[k] = stx * (float)WW - (float)(i0 + k);
            vxy1[k] = sty * (float)HH - (float)j;
            vwh0[k] = logf(stw * (float)WW / ba0);
            vwh1[k] = logf(sth * (float)HH / ba1);
            vwgt[k] = 2.0f - stw * sth;
            float il = fmaxf(bxl[k], stx - stw * 0.5f);
            float ir = fminf(bxr[k], stx + stw * 0.5f);
            float it = fmaxf(byt[k], sty - sth * 0.5f);
            float ib = fminf(byb[k], sty + sth * 0.5f);
            float ov = fmaxf(ir - il, 0.0f) * fmaxf(ib - it, 0.0f);
            vobj[k] = ov / (areap[k] + stw * sth - ov);
            vlab[k] = s_truth[wi * 5 + 4];
            vnoobj[k] = os[k];
        } else {
            vxy0[k] = xs[k];  vxy1[k] = ys[k];
            vwh0[k] = ws[k];  vwh1[k] = hs[k];
            vwgt[k] = 0.0f;
            vobj[k] = os[k];
            vlab[k] = -1.0f;
            vnoobj[k] = ignorable ? os[k] : 0.0f;
        }
    }

    *(float4*)(out + base2)                = make_float4(vxy0[0], vxy0[1], vxy0[2], vxy0[3]);
    *(float4*)(out + base2h)               = make_float4(vxy1[0], vxy1[1], vxy1[2], vxy1[3]);
    *(float4*)(out + N2 + base2)           = make_float4(vwh0[0], vwh0[1], vwh0[2], vwh0[3]);
    *(float4*)(out + N2 + base2h)          = make_float4(vwh1[0], vwh1[1], vwh1[2], vwh1[3]);
    float4 wgt4 = make_float4(vwgt[0], vwgt[1], vwgt[2], vwgt[3]);
    *(float4*)(out + 2 * N2 + base2)       = wgt4;
    *(float4*)(out + 2 * N2 + base2h)      = wgt4;
    *(float4*)(out + 3 * N2 + base1)       = make_float4(vobj[0], vobj[1], vobj[2], vobj[3]);
    *(float4*)(out + 3 * N2 + N1 + base1)  = make_float4(vnoobj[0], vnoobj[1], vnoobj[2], vnoobj[3]);
    *(float4*)(out + 3 * N2 + 2 * N1 + base1) = make_float4(vlab[0], vlab[1], vlab[2], vlab[3]);
}

extern "C" void kernel_launch(void* const* d_in, const int* in_sizes, int n_in,
                              void* d_out, int out_size, void* d_ws, size_t ws_size,
                              hipStream_t stream) {
    const float* xy     = (const float*)d_in[0];
    const float* wh     = (const float*)d_in[1];
    const float* obj    = (const float*)d_in[2];
    const float* truth  = (const float*)d_in[3];
    const float* biases = (const float*)d_in[4];
    float* out = (float*)d_out;

    dim3 grid((AHW + CPB - 1) / CPB, BB);   // (14, 32)
    region_target_fused<<<grid, BLK, 0, stream>>>(xy, wh, obj, truth, biases, out);
}

// Round 5
// 19.742 us; speedup vs baseline: 2.0203x; 1.1833x over previous
//
#include <hip/hip_runtime.h>

// Problem constants (from setup_inputs): B=32, A=5, H=W=52, T=50
#define BB 32
#define AA 5
#define HH 52
#define WW 52
#define TT 50

#define HW (HH * WW)          // 2704
#define AHW (AA * HW)         // 13520
#define N1 (BB * AA * HW)     // 432640
#define N2 (BB * 2 * AA * HW) // 865280

#define CPT 2                  // cells per thread (even i0 -> aligned float2)
#define BLK 256
#define CPB (BLK * CPT)        // 512 cells per block

// ---------------------------------------------------------------------------
// grid = (ceil(AHW/512)=27, B). 864 blocks -> 3456 waves (3.4/SIMD, 2x R4's
// TLP). Single barrier: wave 0 stages truth + tbox/t06 + winner map while
// waves 1..3 issue their global float2 loads (latency hidden under prologue).
// Inner loop: division-free ignorable test (iou>0.6 <=> 1.6*ov-0.6*ta >
// 0.6*areap), unrolled 10 for LDS prefetch. Winner per cell via block-local
// LDS atomicMax (exact argmax-divide semantics preserved).
// ---------------------------------------------------------------------------
__global__ __launch_bounds__(BLK) void region_target_fused(
    const float* __restrict__ xy, const float* __restrict__ wh,
    const float* __restrict__ obj, const float* __restrict__ truth,
    const float* __restrict__ biases, float* __restrict__ out) {
    __shared__ float  s_truth[TT * 5];
    __shared__ float4 s_tbox[TT];     // (txl, txr, tyt, tyb)
    __shared__ float  s_t06[TT];      // 0.6 * tw * th
    __shared__ int    s_win[CPB];     // winner t per local cell, -1 = none

    const int b = blockIdx.y;
    const int tid = threadIdx.x;
    const int cellbase = blockIdx.x * CPB;
    const int c0 = cellbase + tid * CPT;
    const bool active = c0 < AHW;

    // ---- issue global loads EARLY (before barrier) ----
    int a = 0, j = 0, i0 = 0, base2 = 0, base2h = 0, base1 = 0;
    float2 x2 = {0, 0}, y2 = {0, 0}, w2 = {0, 0}, h2 = {0, 0}, o2 = {0, 0};
    float ba0 = 1.0f, ba1 = 1.0f;
    if (active) {
        a = c0 / HW;
        int rem = c0 - a * HW;
        j = rem / WW;
        i0 = rem - j * WW;                       // even -> float2 aligned
        base2  = ((b * 2 * AA + a) * HH + j) * WW + i0;   // x-half
        base2h = base2 + AA * HW;                          // y-half
        base1  = ((b * AA + a) * HH + j) * WW + i0;
        x2 = *(const float2*)(xy + base2);
        y2 = *(const float2*)(xy + base2h);
        w2 = *(const float2*)(wh + base2);
        h2 = *(const float2*)(wh + base2h);
        o2 = *(const float2*)(obj + base1);
        ba0 = biases[2 * a];
        ba1 = biases[2 * a + 1];
    }

    // ---- wave-0 prologue, single barrier ----
    if (tid < 64) {
#pragma unroll
        for (int k = 0; k < CPB / 64; ++k) s_win[tid + k * 64] = -1;
    }
    if (tid < TT) {
        const float* tr = truth + (b * TT + tid) * 5;
        float tx = tr[0], ty = tr[1], tw = tr[2], th = tr[3], tc = tr[4];
        s_truth[tid * 5 + 0] = tx;
        s_truth[tid * 5 + 1] = ty;
        s_truth[tid * 5 + 2] = tw;
        s_truth[tid * 5 + 3] = th;
        s_truth[tid * 5 + 4] = tc;
        s_tbox[tid] = make_float4(tx - tw * 0.5f, tx + tw * 0.5f,
                                  ty - th * 0.5f, ty + th * 0.5f);
        s_t06[tid] = 0.6f * (tw * th);

        // argmax over anchors (exact divide, first max wins == jnp.argmax)
        float best = -1.0f;
        int n = 0;
#pragma unroll
        for (int aa = 0; aa < AA; ++aa) {
            float bw0 = biases[2 * aa] / (float)WW;      // uniform -> s_load
            float bh0 = biases[2 * aa + 1] / (float)HH;
            float il2 = fmaxf(-bw0 * 0.5f, -tw * 0.5f);
            float ir2 = fminf(bw0 * 0.5f, tw * 0.5f);
            float it2 = fmaxf(-bh0 * 0.5f, -th * 0.5f);
            float ib2 = fminf(bh0 * 0.5f, th * 0.5f);
            float ov2 = fmaxf(ir2 - il2, 0.0f) * fmaxf(ib2 - it2, 0.0f);
            float iou2 = ov2 / (bw0 * bh0 + tw * th - ov2);
            if (iou2 > best) { best = iou2; n = aa; }
        }
        int ti = (int)(tx * (float)WW);   // trunc == astype(int32) for tx>0
        int tj = (int)(ty * (float)HH);
        bool invalid_pos = (tx <= 0.0f) || (tx >= 1.0f) || (ty <= 0.0f) || (ty >= 1.0f);
        bool valid = !invalid_pos && ti >= 0 && tj >= 0 && ti < WW && tj < HH &&
                     (tw > 0.0f) && (th > 0.0f);
        if (valid) {
            int local = (n * HH + tj) * WW + ti - cellbase;
            if (local >= 0 && local < CPB) atomicMax(&s_win[local], tid);
        }
    }
    __syncthreads();
    if (!active) return;

    float xs[CPT] = {x2.x, x2.y};
    float ys[CPT] = {y2.x, y2.y};
    float hw_w[CPT] = {w2.x, w2.y};
    float hw_h[CPT] = {h2.x, h2.y};
    float os_[CPT] = {o2.x, o2.y};

    float bxl[CPT], bxr[CPT], byt[CPT], byb[CPT], areap[CPT], m[CPT];
#pragma unroll
    for (int k = 0; k < CPT; ++k) {
        float bx = (xs[k] + (float)(i0 + k)) / (float)WW;   // exact ref order
        float by = (ys[k] + (float)j) / (float)HH;
        float bw = expf(hw_w[k]) * ba0 / (float)WW;
        float bh = expf(hw_h[k]) * ba1 / (float)HH;
        bxl[k] = bx - bw * 0.5f; bxr[k] = bx + bw * 0.5f;
        byt[k] = by - bh * 0.5f; byb[k] = by + bh * 0.5f;
        areap[k] = bw * bh;
        m[k] = -1e30f;
    }

    // division-free: iou>0.6 <=> 1.6*ov - 0.6*tarea > 0.6*areap (union>0)
#pragma unroll 10
    for (int t = 0; t < TT; ++t) {
        float4 tb = s_tbox[t];
        float t06 = s_t06[t];
#pragma unroll
        for (int k = 0; k < CPT; ++k) {
            float il = fmaxf(bxl[k], tb.x);
            float ir = fminf(bxr[k], tb.y);
            float it = fmaxf(byt[k], tb.z);
            float ib = fminf(byb[k], tb.w);
            float ov = fmaxf(ir - il, 0.0f) * fmaxf(ib - it, 0.0f);
            m[k] = fmaxf(m[k], fmaf(1.6f, ov, -t06));
        }
    }

    float vxy0[CPT], vxy1[CPT], vwh0[CPT], vwh1[CPT], vwgt[CPT];
    float vobj[CPT], vnoobj[CPT], vlab[CPT];
#pragma unroll
    for (int k = 0; k < CPT; ++k) {
        bool ignorable = m[k] > 0.6f * areap[k];
        int wsel = s_win[tid * CPT + k];
        bool has = wsel >= 0;
        if (has) {
            int wi = wsel;
            float stx  = s_truth[wi * 5 + 0];
            float sty  = s_truth[wi * 5 + 1];
            float stw  = s_truth[wi * 5 + 2];
            float sth  = s_truth[wi * 5 + 3];
            vxy0[k] = stx * (float)WW - (float)(i0 + k);
            vxy1[k] = sty * (float)HH - (float)j;
            vwh0[k] = logf(stw * (float)WW / ba0);
            vwh1[k] = logf(sth * (float)HH / ba1);
            vwgt[k] = 2.0f - stw * sth;
            float il = fmaxf(bxl[k], stx - stw * 0.5f);
            float ir = fminf(bxr[k], stx + stw * 0.5f);
            float it = fmaxf(byt[k], sty - sth * 0.5f);
            float ib = fminf(byb[k], sty + sth * 0.5f);
            float ov = fmaxf(ir - il, 0.0f) * fmaxf(ib - it, 0.0f);
            vobj[k] = ov / (areap[k] + stw * sth - ov);   // exact rescore divide
            vlab[k] = s_truth[wi * 5 + 4];
            vnoobj[k] = os_[k];
        } else {
            vxy0[k] = xs[k];  vxy1[k] = ys[k];
            vwh0[k] = hw_w[k]; vwh1[k] = hw_h[k];
            vwgt[k] = 0.0f;
            vobj[k] = os_[k];
            vlab[k] = -1.0f;
            vnoobj[k] = ignorable ? os_[k] : 0.0f;
        }
    }

    *(float2*)(out + base2)                   = make_float2(vxy0[0], vxy0[1]);
    *(float2*)(out + base2h)                  = make_float2(vxy1[0], vxy1[1]);
    *(float2*)(out + N2 + base2)              = make_float2(vwh0[0], vwh0[1]);
    *(float2*)(out + N2 + base2h)             = make_float2(vwh1[0], vwh1[1]);
    float2 wgt2 = make_float2(vwgt[0], vwgt[1]);
    *(float2*)(out + 2 * N2 + base2)          = wgt2;
    *(float2*)(out + 2 * N2 + base2h)         = wgt2;
    *(float2*)(out + 3 * N2 + base1)          = make_float2(vobj[0], vobj[1]);
    *(float2*)(out + 3 * N2 + N1 + base1)     = make_float2(vnoobj[0], vnoobj[1]);
    *(float2*)(out + 3 * N2 + 2 * N1 + base1) = make_float2(vlab[0], vlab[1]);
}

extern "C" void kernel_launch(void* const* d_in, const int* in_sizes, int n_in,
                              void* d_out, int out_size, void* d_ws, size_t ws_size,
                              hipStream_t stream) {
    const float* xy     = (const float*)d_in[0];
    const float* wh     = (const float*)d_in[1];
    const float* obj    = (const float*)d_in[2];
    const float* truth  = (const float*)d_in[3];
    const float* biases = (const float*)d_in[4];
    float* out = (float*)d_out;

    dim3 grid((AHW + CPB - 1) / CPB, BB);   // (27, 32)
    region_target_fused<<<grid, BLK, 0, stream>>>(xy, wh, obj, truth, biases, out);
}